// Round 2
// baseline (3924.130 us; speedup 1.0000x reference)
//
#include <hip/hip_runtime.h>

typedef __bf16 bf16;
typedef __bf16 bf16x8 __attribute__((ext_vector_type(8)));
typedef float floatx4 __attribute__((ext_vector_type(4)));

#define LDS_ASYNC(gptr, lptr) \
  __builtin_amdgcn_global_load_lds((const __attribute__((address_space(1))) void*)(gptr), \
                                   (__attribute__((address_space(3))) void*)(lptr), 16, 0, 0)

__device__ __forceinline__ float sigmoid_fast(float x) {
  return 1.0f / (1.0f + __expf(-x));
}

// ---------------------------------------------------------------------------
// f32 -> bf16 conversion (4 elems/thread; all sizes divisible by 4)
// ---------------------------------------------------------------------------
__global__ __launch_bounds__(256)
void cvt_f32_bf16(const float* __restrict__ src, bf16* __restrict__ dst, int n)
{
  const int i = (blockIdx.x * 256 + threadIdx.x) * 4;
  if (i < n) {
    const float4 v = *reinterpret_cast<const float4*>(src + i);
    dst[i]     = (bf16)v.x;
    dst[i + 1] = (bf16)v.y;
    dst[i + 2] = (bf16)v.z;
    dst[i + 3] = (bf16)v.w;
  }
}

// ---------------------------------------------------------------------------
// Generic MFMA GEMM:  C[m,n] = sum_k A[m,k] * W[n,k]
//   A: M x K bf16 (lda), W: wrows x K bf16 (ldw). M fixed = 4096 (grid.x=32).
//   128x128 tile, BK=32, 16x16x32 bf16 MFMA, global_load_lds width-16 staging.
//   W row index clamped to wrows-1 (for N tiles past wrows); stores guarded by
//   col < Nstore.
// MODE 0: store bf16
// MODE 1: store f32
// MODE 2: store bf16( silu(acc + bias[n]) )             (ff1)
// MODE 3: store f32 ( softplus(acc + bias[n]) )         (dt)
// MODE 4: store f32 ( acc + bias[n] + resid[m,n] )      (final out)
// ---------------------------------------------------------------------------
template<int MODE>
__global__ __launch_bounds__(256)
void gemm_bt(const bf16* __restrict__ A, int lda,
             const bf16* __restrict__ W, int ldw, int wrows,
             void* __restrict__ Cp, int ldc,
             const float* __restrict__ bias,
             const float* __restrict__ resid,
             int Nstore, int K)
{
  __shared__ __align__(16) bf16 As[128 * 32];
  __shared__ __align__(16) bf16 Bs[128 * 32];

  const int tid = threadIdx.x;
  const int m0 = blockIdx.x * 128;
  const int n0 = blockIdx.y * 128;

  // staging: thread t loads one 16B chunk per stage; LDS offset = t*16 bytes
  // (wave-uniform base + lane*16 — required by global_load_lds)
  const int srow  = tid >> 2;         // 0..63
  const int skcol = (tid & 3) * 8;    // 0,8,16,24

  int wr0 = n0 + srow;      if (wr0 > wrows - 1) wr0 = wrows - 1;
  int wr1 = n0 + 64 + srow; if (wr1 > wrows - 1) wr1 = wrows - 1;

  floatx4 acc[4][4];
#pragma unroll
  for (int i = 0; i < 4; ++i)
#pragma unroll
    for (int j = 0; j < 4; ++j)
      acc[i][j] = (floatx4){0.f, 0.f, 0.f, 0.f};

  const int wave = tid >> 6;
  const int lane = tid & 63;
  const int quad = lane >> 4;
  const int l16  = lane & 15;
  const int wm = (wave & 1) * 64;
  const int wn = (wave >> 1) * 64;

  for (int k0 = 0; k0 < K; k0 += 32) {
    __syncthreads();
    LDS_ASYNC(A + (size_t)(m0 + srow) * lda + k0 + skcol,      &As[srow * 32 + skcol]);
    LDS_ASYNC(A + (size_t)(m0 + 64 + srow) * lda + k0 + skcol, &As[(64 + srow) * 32 + skcol]);
    LDS_ASYNC(W + (size_t)wr0 * ldw + k0 + skcol,              &Bs[srow * 32 + skcol]);
    LDS_ASYNC(W + (size_t)wr1 * ldw + k0 + skcol,              &Bs[(64 + srow) * 32 + skcol]);
    __builtin_amdgcn_s_waitcnt(0);
    __syncthreads();

    bf16x8 af[4], bfr[4];
#pragma unroll
    for (int i = 0; i < 4; ++i)
      af[i] = *reinterpret_cast<const bf16x8*>(&As[(wm + i * 16 + l16) * 32 + quad * 8]);
#pragma unroll
    for (int j = 0; j < 4; ++j)
      bfr[j] = *reinterpret_cast<const bf16x8*>(&Bs[(wn + j * 16 + l16) * 32 + quad * 8]);
#pragma unroll
    for (int i = 0; i < 4; ++i)
#pragma unroll
      for (int j = 0; j < 4; ++j)
        acc[i][j] = __builtin_amdgcn_mfma_f32_16x16x32_bf16(af[i], bfr[j], acc[i][j], 0, 0, 0);
  }

  // epilogue — C/D layout: col = lane&15, row = quad*4 + reg  [m89-verified]
#pragma unroll
  for (int j = 0; j < 4; ++j) {
    const int col = n0 + wn + j * 16 + l16;
    if (col < Nstore) {
      float bv = 0.0f;
      if (MODE == 2 || MODE == 3 || MODE == 4) bv = bias[col];
#pragma unroll
      for (int i = 0; i < 4; ++i) {
#pragma unroll
        for (int r = 0; r < 4; ++r) {
          const int row = m0 + wm + i * 16 + quad * 4 + r;
          const size_t off = (size_t)row * ldc + col;
          float v = acc[i][j][r];
          if (MODE == 0)      ((bf16*)Cp)[off] = (bf16)v;
          else if (MODE == 1) ((float*)Cp)[off] = v;
          else if (MODE == 2) { v += bv; ((bf16*)Cp)[off] = (bf16)(v * sigmoid_fast(v)); }
          else if (MODE == 3) { v += bv; ((float*)Cp)[off] = (v > 20.f) ? v : log1pf(__expf(v)); }
          else                { v += bv + resid[off]; ((float*)Cp)[off] = v; }
        }
      }
    }
  }
}

// ---------------------------------------------------------------------------
// Depthwise causal conv (k=4) + bias + silu. dir=0: causal (taps l-3..l,
// weights w0..w3). dir=1: anti-causal reversed (xc_b[p] = sum_j w[j]*xi[p+3-j]),
// which implements conv-on-flipped-sequence re-expressed in original order.
// xz is (4096 x 4096) bf16; xi = cols [0,2048). xc out: (4096 x 2048) bf16.
// ---------------------------------------------------------------------------
__global__ __launch_bounds__(256)
void conv_silu_kernel(const bf16* __restrict__ xz, const float* __restrict__ cw,
                      const float* __restrict__ cb, bf16* __restrict__ xc, int dir)
{
  const int idx = blockIdx.x * 256 + threadIdx.x;   // 4096*2048 total
  const int d   = idx & 2047;
  const int pos = idx >> 11;       // 0..4095
  const int l   = pos & 2047;
  const int b   = pos >> 11;
  float w[4];
#pragma unroll
  for (int j = 0; j < 4; ++j) w[j] = cw[d * 4 + j];
  float acc = cb[d];
  if (dir == 0) {
#pragma unroll
    for (int j = 0; j < 4; ++j) {
      const int ll = l - 3 + j;
      if (ll >= 0) acc += w[j] * (float)xz[((size_t)((b << 11) + ll) << 12) + d];
    }
  } else {
#pragma unroll
    for (int j = 0; j < 4; ++j) {
      const int ll = l + 3 - j;
      if (ll < 2048) acc += w[j] * (float)xz[((size_t)((b << 11) + ll) << 12) + d];
    }
  }
  xc[(size_t)pos * 2048 + d] = (bf16)(acc * sigmoid_fast(acc));
}

// ---------------------------------------------------------------------------
// Selective scan, thread per (b, d, s): 16 lanes per channel, h in a register.
// Fused epilogue: yg = (y + u*D) * silu(z)  -> bf16. dir=1 runs time reversed.
// ---------------------------------------------------------------------------
__global__ __launch_bounds__(256)
void scan_kernel(const float* __restrict__ dt, const bf16* __restrict__ xc,
                 const bf16* __restrict__ xdbl, const bf16* __restrict__ xz,
                 const float* __restrict__ A_log, const float* __restrict__ Dp,
                 bf16* __restrict__ yg, int dir)
{
  const int tid = threadIdx.x;
  const int s = tid & 15;
  const int c = tid >> 4;                      // 0..15 local channel
  const int g = blockIdx.x * 16 + c;           // 0..4095
  const int b = g >> 11;
  const int d = g & 2047;

  const float Av = -expf(A_log[d * 16 + s]);
  const float Dv = Dp[d];
  const size_t base_b = (size_t)b << 11;

  float h = 0.0f;
  for (int t = 0; t < 2048; ++t) {
    const int l = dir ? (2047 - t) : t;
    const size_t row = base_b + l;
    const float dtv = dt[row * 2048 + d];
    const float uf  = (float)xc[row * 2048 + d];
    const float Bv  = (float)xdbl[row * 96 + 64 + s];
    const float Cv  = (float)xdbl[row * 96 + 80 + s];
    h = h * __expf(dtv * Av) + (dtv * uf) * Bv;
    float y = h * Cv;
    y += __shfl_xor(y, 8);
    y += __shfl_xor(y, 4);
    y += __shfl_xor(y, 2);
    y += __shfl_xor(y, 1);
    if (s == 0) {
      const float zv = (float)xz[row * 4096 + 2048 + d];
      const float out = (y + uf * Dv) * (zv * sigmoid_fast(zv));
      yg[row * 2048 + d] = (bf16)out;
    }
  }
}

// ---------------------------------------------------------------------------
// x1 = x + 0.5*(ym_f + ym_b); store x1 (f32) and LayerNorm(x1)*g+b (bf16).
// One block per row (1024 cols, 256 threads x 4).
// ---------------------------------------------------------------------------
__global__ __launch_bounds__(256)
void combine_ln_kernel(const float* __restrict__ x, const float* __restrict__ ymf,
                       const float* __restrict__ ymb, const float* __restrict__ gg,
                       const float* __restrict__ bb, float* __restrict__ x1,
                       bf16* __restrict__ ln)
{
  const int r = blockIdx.x;
  const int tid = threadIdx.x;
  const size_t base = (size_t)r * 1024;
  float v[4];
  float sum = 0.f, sq = 0.f;
#pragma unroll
  for (int i = 0; i < 4; ++i) {
    const int c = tid + i * 256;
    const float t = x[base + c] + 0.5f * (ymf[base + c] + ymb[base + c]);
    v[i] = t; sum += t; sq += t * t;
    x1[base + c] = t;
  }
#pragma unroll
  for (int off = 32; off >= 1; off >>= 1) {
    sum += __shfl_xor(sum, off);
    sq  += __shfl_xor(sq, off);
  }
  __shared__ float s1[4], s2[4];
  const int wave = tid >> 6, lane = tid & 63;
  if (lane == 0) { s1[wave] = sum; s2[wave] = sq; }
  __syncthreads();
  sum = s1[0] + s1[1] + s1[2] + s1[3];
  sq  = s2[0] + s2[1] + s2[2] + s2[3];
  const float mean = sum * (1.0f / 1024.0f);
  const float var  = sq * (1.0f / 1024.0f) - mean * mean;
  const float rs   = rsqrtf(var + 1e-5f);
#pragma unroll
  for (int i = 0; i < 4; ++i) {
    const int c = tid + i * 256;
    ln[base + c] = (bf16)((v[i] - mean) * rs * gg[c] + bb[c]);
  }
}

// ---------------------------------------------------------------------------
extern "C" void kernel_launch(void* const* d_in, const int* in_sizes, int n_in,
                              void* d_out, int out_size, void* d_ws, size_t ws_size,
                              hipStream_t stream)
{
  (void)in_sizes; (void)n_in; (void)out_size; (void)ws_size;

  const float* x      = (const float*)d_in[0];
  const float* ff_ln_g = (const float*)d_in[19];
  const float* ff_ln_b = (const float*)d_in[20];
  const float* ff_w1   = (const float*)d_in[21];
  const float* ff_b1   = (const float*)d_in[22];
  const float* ff_w2   = (const float*)d_in[23];
  const float* ff_b2   = (const float*)d_in[24];

  char* ws = (char*)d_ws;
  size_t off = 0;
  auto alloc = [&](size_t bytes) -> void* {
    void* p = ws + off;
    off += (bytes + 255) & ~(size_t)255;
    return p;
  };
  // M = B*L = 4096 rows everywhere
  bf16*  xz    = (bf16*) alloc((size_t)4096 * 4096 * 2);  // in_proj out (xi | z)
  bf16*  xc    = (bf16*) alloc((size_t)4096 * 2048 * 2);  // conv+silu out
  bf16*  xdbl  = (bf16*) alloc((size_t)4096 * 96 * 2);    // x_proj out
  float* dtb   = (float*)alloc((size_t)4096 * 2048 * 4);  // softplus(dt)
  bf16*  yg    = (bf16*) alloc((size_t)4096 * 2048 * 2);  // gated scan out
  float* ymf   = (float*)alloc((size_t)4096 * 1024 * 4);  // fwd mamba out
  float* ymb   = (float*)alloc((size_t)4096 * 1024 * 4);  // bwd mamba out
  bf16*  xb    = (bf16*) alloc((size_t)4096 * 1024 * 2);  // x as bf16
  bf16*  in_wb = (bf16*) alloc((size_t)4096 * 1024 * 2);  // per-dir in_w bf16
  bf16*  x_wb  = (bf16*) alloc((size_t)96 * 2048 * 2);    // per-dir x_w bf16
  bf16*  dt_wb = (bf16*) alloc((size_t)2048 * 64 * 2);    // per-dir dt_w bf16
  bf16*  out_wb= (bf16*) alloc((size_t)1024 * 2048 * 2);  // per-dir out_w bf16
  // phase-ordered aliases (safe: prior users finish before these are written)
  float* x1     = (float*)dtb;   // residual after mamba combine (16MB <= 32MB)
  bf16*  ln     = xc;            // layernorm output (8MB <= 16MB)
  bf16*  h1     = xz;            // ff1 output (32MB == 32MB)
  bf16*  ff_w1b = in_wb;         // in_wb dead after bwd in_proj GEMM (8MB == 8MB)
  bf16*  ff_w2b = xb;            // xb dead after bwd in_proj GEMM   (8MB == 8MB)

  // x -> bf16 (once)
  cvt_f32_bf16<<<4096, 256, 0, stream>>>(x, xb, 4096 * 1024);

  for (int dir = 0; dir < 2; ++dir) {
    const float* in_w   = (const float*)d_in[1 + dir * 9 + 0];
    const float* conv_w = (const float*)d_in[1 + dir * 9 + 1];
    const float* conv_b = (const float*)d_in[1 + dir * 9 + 2];
    const float* x_w    = (const float*)d_in[1 + dir * 9 + 3];
    const float* dt_w   = (const float*)d_in[1 + dir * 9 + 4];
    const float* dt_b   = (const float*)d_in[1 + dir * 9 + 5];
    const float* A_log  = (const float*)d_in[1 + dir * 9 + 6];
    const float* Dp     = (const float*)d_in[1 + dir * 9 + 7];
    const float* out_w  = (const float*)d_in[1 + dir * 9 + 8];

    // weight conversions for this direction
    cvt_f32_bf16<<<4096, 256, 0, stream>>>(in_w,  in_wb,  4096 * 1024);
    cvt_f32_bf16<<<192,  256, 0, stream>>>(x_w,   x_wb,   96 * 2048);
    cvt_f32_bf16<<<128,  256, 0, stream>>>(dt_w,  dt_wb,  2048 * 64);
    cvt_f32_bf16<<<2048, 256, 0, stream>>>(out_w, out_wb, 1024 * 2048);

    // xz = x @ in_w^T   (4096 x 4096, K=1024)
    gemm_bt<0><<<dim3(32, 32), 256, 0, stream>>>(xb, 1024, in_wb, 1024, 4096,
                                                 xz, 4096, nullptr, nullptr, 4096, 1024);
    // depthwise conv + silu
    conv_silu_kernel<<<32768, 256, 0, stream>>>(xz, conv_w, conv_b, xc, dir);
    // xdbl = xc @ x_w^T   (4096 x 96, K=2048)
    gemm_bt<0><<<dim3(32, 1), 256, 0, stream>>>(xc, 2048, x_wb, 2048, 96,
                                                xdbl, 96, nullptr, nullptr, 96, 2048);
    // dt = softplus(xdbl[:, :64] @ dt_w^T + dt_b)   (4096 x 2048, K=64)
    gemm_bt<3><<<dim3(32, 16), 256, 0, stream>>>(xdbl, 96, dt_wb, 64, 2048,
                                                 dtb, 2048, dt_b, nullptr, 2048, 64);
    // selective scan + gate fusion
    scan_kernel<<<256, 256, 0, stream>>>(dtb, xc, xdbl, xz, A_log, Dp, yg, dir);
    // ym = yg @ out_w^T   (4096 x 1024, K=2048)
    gemm_bt<1><<<dim3(32, 8), 256, 0, stream>>>(yg, 2048, out_wb, 2048, 1024,
                                                dir ? (void*)ymb : (void*)ymf, 1024,
                                                nullptr, nullptr, 1024, 2048);
  }

  // ff weight conversions (into buffers dead after the dir loop)
  cvt_f32_bf16<<<4096, 256, 0, stream>>>(ff_w1, ff_w1b, 4096 * 1024);
  cvt_f32_bf16<<<4096, 256, 0, stream>>>(ff_w2, ff_w2b, 1024 * 4096);

  // x1 = x + 0.5*(ymf+ymb); ln = LN(x1)*g+b
  combine_ln_kernel<<<4096, 256, 0, stream>>>(x, ymf, ymb, ff_ln_g, ff_ln_b, x1, ln);
  // h1 = silu(ln @ ff_w1^T + b1)   (4096 x 4096, K=1024)
  gemm_bt<2><<<dim3(32, 32), 256, 0, stream>>>(ln, 1024, ff_w1b, 1024, 4096,
                                               h1, 4096, ff_b1, nullptr, 4096, 1024);
  // out = x1 + h1 @ ff_w2^T + b2   (4096 x 1024, K=4096) -> d_out (f32)
  gemm_bt<4><<<dim3(32, 8), 256, 0, stream>>>(h1, 4096, ff_w2b, 4096, 1024,
                                              d_out, 1024, ff_b2, x1, 1024, 4096);
}

// Round 3
// 1338.317 us; speedup vs baseline: 2.9321x; 2.9321x over previous
//
#include <hip/hip_runtime.h>

typedef __bf16 bf16;
typedef __bf16 bf16x8 __attribute__((ext_vector_type(8)));
typedef float floatx4 __attribute__((ext_vector_type(4)));

#define LDS_ASYNC(gptr, lptr) \
  __builtin_amdgcn_global_load_lds((const __attribute__((address_space(1))) void*)(gptr), \
                                   (__attribute__((address_space(3))) void*)(lptr), 16, 0, 0)

__device__ __forceinline__ float sigmoid_fast(float x) {
  return 1.0f / (1.0f + __expf(-x));
}

// Chunked scan parameters: L=2048 = NCHUNK * CHUNK
#define CHUNK  64
#define NCHUNK 32

// ---------------------------------------------------------------------------
// f32 -> bf16 conversion (4 elems/thread; all sizes divisible by 4)
// ---------------------------------------------------------------------------
__global__ __launch_bounds__(256)
void cvt_f32_bf16(const float* __restrict__ src, bf16* __restrict__ dst, int n)
{
  const int i = (blockIdx.x * 256 + threadIdx.x) * 4;
  if (i < n) {
    const float4 v = *reinterpret_cast<const float4*>(src + i);
    dst[i]     = (bf16)v.x;
    dst[i + 1] = (bf16)v.y;
    dst[i + 2] = (bf16)v.z;
    dst[i + 3] = (bf16)v.w;
  }
}

// ---------------------------------------------------------------------------
// Generic MFMA GEMM:  C[m,n] = sum_k A[m,k] * W[n,k]
//   A: M x K bf16 (lda), W: wrows x K bf16 (ldw). M fixed = 4096 (grid.x=32).
//   128x128 tile, BK=32, 16x16x32 bf16 MFMA, global_load_lds width-16 staging.
// MODE 0: store bf16
// MODE 1: store f32
// MODE 2: store bf16( silu(acc + bias[n]) )             (ff1)
// MODE 3: store f32 ( softplus(acc + bias[n]) )         (dt)
// MODE 4: store f32 ( acc + bias[n] + resid[m,n] )      (final out)
// ---------------------------------------------------------------------------
template<int MODE>
__global__ __launch_bounds__(256)
void gemm_bt(const bf16* __restrict__ A, int lda,
             const bf16* __restrict__ W, int ldw, int wrows,
             void* __restrict__ Cp, int ldc,
             const float* __restrict__ bias,
             const float* __restrict__ resid,
             int Nstore, int K)
{
  __shared__ __align__(16) bf16 As[128 * 32];
  __shared__ __align__(16) bf16 Bs[128 * 32];

  const int tid = threadIdx.x;
  const int m0 = blockIdx.x * 128;
  const int n0 = blockIdx.y * 128;

  const int srow  = tid >> 2;         // 0..63
  const int skcol = (tid & 3) * 8;    // 0,8,16,24

  int wr0 = n0 + srow;      if (wr0 > wrows - 1) wr0 = wrows - 1;
  int wr1 = n0 + 64 + srow; if (wr1 > wrows - 1) wr1 = wrows - 1;

  floatx4 acc[4][4];
#pragma unroll
  for (int i = 0; i < 4; ++i)
#pragma unroll
    for (int j = 0; j < 4; ++j)
      acc[i][j] = (floatx4){0.f, 0.f, 0.f, 0.f};

  const int wave = tid >> 6;
  const int lane = tid & 63;
  const int quad = lane >> 4;
  const int l16  = lane & 15;
  const int wm = (wave & 1) * 64;
  const int wn = (wave >> 1) * 64;

  for (int k0 = 0; k0 < K; k0 += 32) {
    __syncthreads();
    LDS_ASYNC(A + (size_t)(m0 + srow) * lda + k0 + skcol,      &As[srow * 32 + skcol]);
    LDS_ASYNC(A + (size_t)(m0 + 64 + srow) * lda + k0 + skcol, &As[(64 + srow) * 32 + skcol]);
    LDS_ASYNC(W + (size_t)wr0 * ldw + k0 + skcol,              &Bs[srow * 32 + skcol]);
    LDS_ASYNC(W + (size_t)wr1 * ldw + k0 + skcol,              &Bs[(64 + srow) * 32 + skcol]);
    __builtin_amdgcn_s_waitcnt(0);
    __syncthreads();

    bf16x8 af[4], bfr[4];
#pragma unroll
    for (int i = 0; i < 4; ++i)
      af[i] = *reinterpret_cast<const bf16x8*>(&As[(wm + i * 16 + l16) * 32 + quad * 8]);
#pragma unroll
    for (int j = 0; j < 4; ++j)
      bfr[j] = *reinterpret_cast<const bf16x8*>(&Bs[(wn + j * 16 + l16) * 32 + quad * 8]);
#pragma unroll
    for (int i = 0; i < 4; ++i)
#pragma unroll
      for (int j = 0; j < 4; ++j)
        acc[i][j] = __builtin_amdgcn_mfma_f32_16x16x32_bf16(af[i], bfr[j], acc[i][j], 0, 0, 0);
  }

  // epilogue — C/D layout: col = lane&15, row = quad*4 + reg  [m89-verified]
#pragma unroll
  for (int j = 0; j < 4; ++j) {
    const int col = n0 + wn + j * 16 + l16;
    if (col < Nstore) {
      float bv = 0.0f;
      if (MODE == 2 || MODE == 3 || MODE == 4) bv = bias[col];
#pragma unroll
      for (int i = 0; i < 4; ++i) {
#pragma unroll
        for (int r = 0; r < 4; ++r) {
          const int row = m0 + wm + i * 16 + quad * 4 + r;
          const size_t off = (size_t)row * ldc + col;
          float v = acc[i][j][r];
          if (MODE == 0)      ((bf16*)Cp)[off] = (bf16)v;
          else if (MODE == 1) ((float*)Cp)[off] = v;
          else if (MODE == 2) { v += bv; ((bf16*)Cp)[off] = (bf16)(v * sigmoid_fast(v)); }
          else if (MODE == 3) { v += bv; ((float*)Cp)[off] = (v > 20.f) ? v : log1pf(__expf(v)); }
          else                { v += bv + resid[off]; ((float*)Cp)[off] = v; }
        }
      }
    }
  }
}

// ---------------------------------------------------------------------------
// Depthwise causal conv (k=4) + bias + silu. dir=0: causal; dir=1 anti-causal
// (equivalent to conv on flipped sequence, expressed in original order).
// ---------------------------------------------------------------------------
__global__ __launch_bounds__(256)
void conv_silu_kernel(const bf16* __restrict__ xz, const float* __restrict__ cw,
                      const float* __restrict__ cb, bf16* __restrict__ xc, int dir)
{
  const int idx = blockIdx.x * 256 + threadIdx.x;   // 4096*2048 total
  const int d   = idx & 2047;
  const int pos = idx >> 11;       // 0..4095
  const int l   = pos & 2047;
  const int b   = pos >> 11;
  float w[4];
#pragma unroll
  for (int j = 0; j < 4; ++j) w[j] = cw[d * 4 + j];
  float acc = cb[d];
  if (dir == 0) {
#pragma unroll
    for (int j = 0; j < 4; ++j) {
      const int ll = l - 3 + j;
      if (ll >= 0) acc += w[j] * (float)xz[((size_t)((b << 11) + ll) << 12) + d];
    }
  } else {
#pragma unroll
    for (int j = 0; j < 4; ++j) {
      const int ll = l + 3 - j;
      if (ll < 2048) acc += w[j] * (float)xz[((size_t)((b << 11) + ll) << 12) + d];
    }
  }
  xc[(size_t)pos * 2048 + d] = (bf16)(acc * sigmoid_fast(acc));
}

// ---------------------------------------------------------------------------
// Chunked selective scan.
// Logical time tau in [0,2048); physical l = dir ? 2047-tau : tau.
// Chunk c covers tau in [c*CHUNK, (c+1)*CHUNK).
//
// S1: per (b,d,s,chunk): local scan from h=0 -> chunk decay product P and
//     local final state F.  P/F layout: [((b*NCHUNK+c)*2048+d)*16+s].
// S2: per (b,d,s): serial over chunks: Hbuf[c] = H; H = F + P*H.
// S3: per (b,d,s,chunk): exact recurrence seeded with Hbuf[c]; y-reduce over
//     the 16 s-lanes; fused gate (y + u*D)*silu(z) -> yg (bf16).
// ---------------------------------------------------------------------------
__global__ __launch_bounds__(256)
void scan_part1(const float* __restrict__ dt, const bf16* __restrict__ xc,
                const bf16* __restrict__ xdbl, const float* __restrict__ A_log,
                float* __restrict__ Pbuf, float* __restrict__ Fbuf, int dir)
{
  const int tid = threadIdx.x;
  const int s = tid & 15;
  const int d = blockIdx.x * 16 + (tid >> 4);
  const int c = blockIdx.y;
  const int b = blockIdx.z;

  const float Av = -expf(A_log[d * 16 + s]);
  const size_t base_b = (size_t)b << 11;

  float h = 0.0f, P = 1.0f;
#pragma unroll 4
  for (int ti = 0; ti < CHUNK; ++ti) {
    const int tau = c * CHUNK + ti;
    const int l = dir ? (2047 - tau) : tau;
    const size_t row = base_b + l;
    const float dtv = dt[row * 2048 + d];
    const float uf  = (float)xc[row * 2048 + d];
    const float Bv  = (float)xdbl[row * 96 + 64 + s];
    const float e = __expf(dtv * Av);
    h = h * e + (dtv * uf) * Bv;
    P *= e;
  }
  const size_t off = (((size_t)(b * NCHUNK + c) * 2048) + d) * 16 + s;
  Pbuf[off] = P;
  Fbuf[off] = h;
}

__global__ __launch_bounds__(256)
void scan_part2(const float* __restrict__ Pbuf, const float* __restrict__ Fbuf,
                float* __restrict__ Hbuf)
{
  const int idx = blockIdx.x * 256 + threadIdx.x;  // 65536 total
  const int s = idx & 15;
  const int d = (idx >> 4) & 2047;
  const int b = idx >> 15;
  float H = 0.0f;
  for (int c = 0; c < NCHUNK; ++c) {
    const size_t off = (((size_t)(b * NCHUNK + c) * 2048) + d) * 16 + s;
    Hbuf[off] = H;
    H = Fbuf[off] + Pbuf[off] * H;
  }
}

__global__ __launch_bounds__(256)
void scan_part3(const float* __restrict__ dt, const bf16* __restrict__ xc,
                const bf16* __restrict__ xdbl, const bf16* __restrict__ xz,
                const float* __restrict__ A_log, const float* __restrict__ Dp,
                const float* __restrict__ Hbuf, bf16* __restrict__ yg, int dir)
{
  const int tid = threadIdx.x;
  const int s = tid & 15;
  const int d = blockIdx.x * 16 + (tid >> 4);
  const int c = blockIdx.y;
  const int b = blockIdx.z;

  const float Av = -expf(A_log[d * 16 + s]);
  const float Dv = Dp[d];
  const size_t base_b = (size_t)b << 11;

  float h = Hbuf[(((size_t)(b * NCHUNK + c) * 2048) + d) * 16 + s];
  for (int ti = 0; ti < CHUNK; ++ti) {
    const int tau = c * CHUNK + ti;
    const int l = dir ? (2047 - tau) : tau;
    const size_t row = base_b + l;
    const float dtv = dt[row * 2048 + d];
    const float uf  = (float)xc[row * 2048 + d];
    const float Bv  = (float)xdbl[row * 96 + 64 + s];
    const float Cv  = (float)xdbl[row * 96 + 80 + s];
    h = h * __expf(dtv * Av) + (dtv * uf) * Bv;
    float y = h * Cv;
    y += __shfl_xor(y, 8);
    y += __shfl_xor(y, 4);
    y += __shfl_xor(y, 2);
    y += __shfl_xor(y, 1);
    if (s == 0) {
      const float zv = (float)xz[row * 4096 + 2048 + d];
      const float out = (y + uf * Dv) * (zv * sigmoid_fast(zv));
      yg[row * 2048 + d] = (bf16)out;
    }
  }
}

// ---------------------------------------------------------------------------
// x1 = x + 0.5*(ym_f + ym_b); store x1 (f32) and LayerNorm(x1)*g+b (bf16).
// ---------------------------------------------------------------------------
__global__ __launch_bounds__(256)
void combine_ln_kernel(const float* __restrict__ x, const float* __restrict__ ymf,
                       const float* __restrict__ ymb, const float* __restrict__ gg,
                       const float* __restrict__ bb, float* __restrict__ x1,
                       bf16* __restrict__ ln)
{
  const int r = blockIdx.x;
  const int tid = threadIdx.x;
  const size_t base = (size_t)r * 1024;
  float v[4];
  float sum = 0.f, sq = 0.f;
#pragma unroll
  for (int i = 0; i < 4; ++i) {
    const int c = tid + i * 256;
    const float t = x[base + c] + 0.5f * (ymf[base + c] + ymb[base + c]);
    v[i] = t; sum += t; sq += t * t;
    x1[base + c] = t;
  }
#pragma unroll
  for (int off = 32; off >= 1; off >>= 1) {
    sum += __shfl_xor(sum, off);
    sq  += __shfl_xor(sq, off);
  }
  __shared__ float s1[4], s2[4];
  const int wave = tid >> 6, lane = tid & 63;
  if (lane == 0) { s1[wave] = sum; s2[wave] = sq; }
  __syncthreads();
  sum = s1[0] + s1[1] + s1[2] + s1[3];
  sq  = s2[0] + s2[1] + s2[2] + s2[3];
  const float mean = sum * (1.0f / 1024.0f);
  const float var  = sq * (1.0f / 1024.0f) - mean * mean;
  const float rs   = rsqrtf(var + 1e-5f);
#pragma unroll
  for (int i = 0; i < 4; ++i) {
    const int c = tid + i * 256;
    ln[base + c] = (bf16)((v[i] - mean) * rs * gg[c] + bb[c]);
  }
}

// ---------------------------------------------------------------------------
extern "C" void kernel_launch(void* const* d_in, const int* in_sizes, int n_in,
                              void* d_out, int out_size, void* d_ws, size_t ws_size,
                              hipStream_t stream)
{
  (void)in_sizes; (void)n_in; (void)out_size; (void)ws_size;

  const float* x      = (const float*)d_in[0];
  const float* ff_ln_g = (const float*)d_in[19];
  const float* ff_ln_b = (const float*)d_in[20];
  const float* ff_w1   = (const float*)d_in[21];
  const float* ff_b1   = (const float*)d_in[22];
  const float* ff_w2   = (const float*)d_in[23];
  const float* ff_b2   = (const float*)d_in[24];

  char* ws = (char*)d_ws;
  size_t off = 0;
  auto alloc = [&](size_t bytes) -> void* {
    void* p = ws + off;
    off += (bytes + 255) & ~(size_t)255;
    return p;
  };
  // M = B*L = 4096 rows everywhere
  bf16*  xz    = (bf16*) alloc((size_t)4096 * 4096 * 2);  // in_proj out (xi | z)
  bf16*  xc    = (bf16*) alloc((size_t)4096 * 2048 * 2);  // conv+silu out
  bf16*  xdbl  = (bf16*) alloc((size_t)4096 * 96 * 2);    // x_proj out
  float* dtb   = (float*)alloc((size_t)4096 * 2048 * 4);  // softplus(dt)
  bf16*  yg    = (bf16*) alloc((size_t)4096 * 2048 * 2);  // gated scan out
  float* ymf   = (float*)alloc((size_t)4096 * 1024 * 4);  // fwd mamba out
  float* ymb   = (float*)alloc((size_t)4096 * 1024 * 4);  // bwd mamba out
  bf16*  xb    = (bf16*) alloc((size_t)4096 * 1024 * 2);  // x as bf16
  bf16*  in_wb = (bf16*) alloc((size_t)4096 * 1024 * 2);  // per-dir in_w bf16
  bf16*  x_wb  = (bf16*) alloc((size_t)96 * 2048 * 2);    // per-dir x_w bf16
  bf16*  dt_wb = (bf16*) alloc((size_t)2048 * 64 * 2);    // per-dir dt_w bf16
  bf16*  out_wb= (bf16*) alloc((size_t)1024 * 2048 * 2);  // per-dir out_w bf16
  float* Pbuf  = (float*)alloc((size_t)2 * NCHUNK * 2048 * 16 * 4);  // 8MB
  float* Fbuf  = (float*)alloc((size_t)2 * NCHUNK * 2048 * 16 * 4);  // 8MB
  float* Hbuf  = (float*)alloc((size_t)2 * NCHUNK * 2048 * 16 * 4);  // 8MB
  // phase-ordered aliases (safe: prior users finish before these are written)
  float* x1     = (float*)dtb;   // residual after mamba combine
  bf16*  ln     = xc;            // layernorm output
  bf16*  h1     = xz;            // ff1 output
  bf16*  ff_w1b = in_wb;         // in_wb dead after bwd in_proj GEMM
  bf16*  ff_w2b = xb;            // xb dead after bwd in_proj GEMM

  // x -> bf16 (once)
  cvt_f32_bf16<<<4096, 256, 0, stream>>>(x, xb, 4096 * 1024);

  for (int dir = 0; dir < 2; ++dir) {
    const float* in_w   = (const float*)d_in[1 + dir * 9 + 0];
    const float* conv_w = (const float*)d_in[1 + dir * 9 + 1];
    const float* conv_b = (const float*)d_in[1 + dir * 9 + 2];
    const float* x_w    = (const float*)d_in[1 + dir * 9 + 3];
    const float* dt_w   = (const float*)d_in[1 + dir * 9 + 4];
    const float* dt_b   = (const float*)d_in[1 + dir * 9 + 5];
    const float* A_log  = (const float*)d_in[1 + dir * 9 + 6];
    const float* Dp     = (const float*)d_in[1 + dir * 9 + 7];
    const float* out_w  = (const float*)d_in[1 + dir * 9 + 8];

    // weight conversions for this direction
    cvt_f32_bf16<<<4096, 256, 0, stream>>>(in_w,  in_wb,  4096 * 1024);
    cvt_f32_bf16<<<192,  256, 0, stream>>>(x_w,   x_wb,   96 * 2048);
    cvt_f32_bf16<<<128,  256, 0, stream>>>(dt_w,  dt_wb,  2048 * 64);
    cvt_f32_bf16<<<2048, 256, 0, stream>>>(out_w, out_wb, 1024 * 2048);

    // xz = x @ in_w^T   (4096 x 4096, K=1024)
    gemm_bt<0><<<dim3(32, 32), 256, 0, stream>>>(xb, 1024, in_wb, 1024, 4096,
                                                 xz, 4096, nullptr, nullptr, 4096, 1024);
    // depthwise conv + silu
    conv_silu_kernel<<<32768, 256, 0, stream>>>(xz, conv_w, conv_b, xc, dir);
    // xdbl = xc @ x_w^T   (4096 x 96, K=2048)
    gemm_bt<0><<<dim3(32, 1), 256, 0, stream>>>(xc, 2048, x_wb, 2048, 96,
                                                xdbl, 96, nullptr, nullptr, 96, 2048);
    // dt = softplus(xdbl[:, :64] @ dt_w^T + dt_b)   (4096 x 2048, K=64)
    gemm_bt<3><<<dim3(32, 16), 256, 0, stream>>>(xdbl, 96, dt_wb, 64, 2048,
                                                 dtb, 2048, dt_b, nullptr, 2048, 64);
    // chunked selective scan + gate fusion
    scan_part1<<<dim3(128, NCHUNK, 2), 256, 0, stream>>>(dtb, xc, xdbl, A_log,
                                                         Pbuf, Fbuf, dir);
    scan_part2<<<256, 256, 0, stream>>>(Pbuf, Fbuf, Hbuf);
    scan_part3<<<dim3(128, NCHUNK, 2), 256, 0, stream>>>(dtb, xc, xdbl, xz, A_log,
                                                         Dp, Hbuf, yg, dir);
    // ym = yg @ out_w^T   (4096 x 1024, K=2048)
    gemm_bt<1><<<dim3(32, 8), 256, 0, stream>>>(yg, 2048, out_wb, 2048, 1024,
                                                dir ? (void*)ymb : (void*)ymf, 1024,
                                                nullptr, nullptr, 1024, 2048);
  }

  // ff weight conversions (into buffers dead after the dir loop)
  cvt_f32_bf16<<<4096, 256, 0, stream>>>(ff_w1, ff_w1b, 4096 * 1024);
  cvt_f32_bf16<<<4096, 256, 0, stream>>>(ff_w2, ff_w2b, 1024 * 4096);

  // x1 = x + 0.5*(ymf+ymb); ln = LN(x1)*g+b
  combine_ln_kernel<<<4096, 256, 0, stream>>>(x, ymf, ymb, ff_ln_g, ff_ln_b, x1, ln);
  // h1 = silu(ln @ ff_w1^T + b1)   (4096 x 4096, K=1024)
  gemm_bt<2><<<dim3(32, 32), 256, 0, stream>>>(ln, 1024, ff_w1b, 1024, 4096,
                                               h1, 4096, ff_b1, nullptr, 4096, 1024);
  // out = x1 + h1 @ ff_w2^T + b2   (4096 x 1024, K=4096) -> d_out (f32)
  gemm_bt<4><<<dim3(32, 8), 256, 0, stream>>>(h1, 4096, ff_w2b, 4096, 1024,
                                              d_out, 1024, ff_b2, x1, 1024, 4096);
}

// Round 4
// 975.658 us; speedup vs baseline: 4.0220x; 1.3717x over previous
//
#include <hip/hip_runtime.h>

typedef __bf16 bf16;
typedef __bf16 bf16x8 __attribute__((ext_vector_type(8)));
typedef float floatx4 __attribute__((ext_vector_type(4)));

#define LDS_ASYNC(gptr, lptr) \
  __builtin_amdgcn_global_load_lds((const __attribute__((address_space(1))) void*)(gptr), \
                                   (__attribute__((address_space(3))) void*)(lptr), 16, 0, 0)

__device__ __forceinline__ float sigmoid_fast(float x) {
  return 1.0f / (1.0f + __expf(-x));
}

// Chunked scan parameters: L=2048 = NCHUNK * CHUNK
#define CHUNK  64
#define NCHUNK 32

// ---------------------------------------------------------------------------
// f32 -> bf16 conversion (4 elems/thread; all sizes divisible by 4)
// ---------------------------------------------------------------------------
__global__ __launch_bounds__(256)
void cvt_f32_bf16(const float* __restrict__ src, bf16* __restrict__ dst, int n)
{
  const int i = (blockIdx.x * 256 + threadIdx.x) * 4;
  if (i < n) {
    const float4 v = *reinterpret_cast<const float4*>(src + i);
    dst[i]     = (bf16)v.x;
    dst[i + 1] = (bf16)v.y;
    dst[i + 2] = (bf16)v.z;
    dst[i + 3] = (bf16)v.w;
  }
}

// ---------------------------------------------------------------------------
// Generic MFMA GEMM:  C[m,n] = sum_k A[m,k] * W[n,k]
//   A: M x K bf16 (lda), W: wrows x K bf16 (ldw). M fixed = 4096 (grid.x=32).
//   128x128 tile, BK=32, 16x16x32 bf16 MFMA, global_load_lds width-16 staging.
// MODE 0: store bf16
// MODE 1: store f32
// MODE 2: store bf16( silu(acc + bias[n]) )             (ff1)
// MODE 3: store f32 ( softplus(acc + bias[n]) )         (dt)
// MODE 4: store f32 ( acc + bias[n] + resid[m,n] )      (final out)
// ---------------------------------------------------------------------------
template<int MODE>
__global__ __launch_bounds__(256)
void gemm_bt(const bf16* __restrict__ A, int lda,
             const bf16* __restrict__ W, int ldw, int wrows,
             void* __restrict__ Cp, int ldc,
             const float* __restrict__ bias,
             const float* __restrict__ resid,
             int Nstore, int K)
{
  __shared__ __align__(16) bf16 As[128 * 32];
  __shared__ __align__(16) bf16 Bs[128 * 32];

  const int tid = threadIdx.x;
  const int m0 = blockIdx.x * 128;
  const int n0 = blockIdx.y * 128;

  const int srow  = tid >> 2;         // 0..63
  const int skcol = (tid & 3) * 8;    // 0,8,16,24

  int wr0 = n0 + srow;      if (wr0 > wrows - 1) wr0 = wrows - 1;
  int wr1 = n0 + 64 + srow; if (wr1 > wrows - 1) wr1 = wrows - 1;

  floatx4 acc[4][4];
#pragma unroll
  for (int i = 0; i < 4; ++i)
#pragma unroll
    for (int j = 0; j < 4; ++j)
      acc[i][j] = (floatx4){0.f, 0.f, 0.f, 0.f};

  const int wave = tid >> 6;
  const int lane = tid & 63;
  const int quad = lane >> 4;
  const int l16  = lane & 15;
  const int wm = (wave & 1) * 64;
  const int wn = (wave >> 1) * 64;

  for (int k0 = 0; k0 < K; k0 += 32) {
    __syncthreads();
    LDS_ASYNC(A + (size_t)(m0 + srow) * lda + k0 + skcol,      &As[srow * 32 + skcol]);
    LDS_ASYNC(A + (size_t)(m0 + 64 + srow) * lda + k0 + skcol, &As[(64 + srow) * 32 + skcol]);
    LDS_ASYNC(W + (size_t)wr0 * ldw + k0 + skcol,              &Bs[srow * 32 + skcol]);
    LDS_ASYNC(W + (size_t)wr1 * ldw + k0 + skcol,              &Bs[(64 + srow) * 32 + skcol]);
    __builtin_amdgcn_s_waitcnt(0);
    __syncthreads();

    bf16x8 af[4], bfr[4];
#pragma unroll
    for (int i = 0; i < 4; ++i)
      af[i] = *reinterpret_cast<const bf16x8*>(&As[(wm + i * 16 + l16) * 32 + quad * 8]);
#pragma unroll
    for (int j = 0; j < 4; ++j)
      bfr[j] = *reinterpret_cast<const bf16x8*>(&Bs[(wn + j * 16 + l16) * 32 + quad * 8]);
#pragma unroll
    for (int i = 0; i < 4; ++i)
#pragma unroll
      for (int j = 0; j < 4; ++j)
        acc[i][j] = __builtin_amdgcn_mfma_f32_16x16x32_bf16(af[i], bfr[j], acc[i][j], 0, 0, 0);
  }

  // epilogue — C/D layout: col = lane&15, row = quad*4 + reg  [m89-verified]
#pragma unroll
  for (int j = 0; j < 4; ++j) {
    const int col = n0 + wn + j * 16 + l16;
    if (col < Nstore) {
      float bv = 0.0f;
      if (MODE == 2 || MODE == 3 || MODE == 4) bv = bias[col];
#pragma unroll
      for (int i = 0; i < 4; ++i) {
#pragma unroll
        for (int r = 0; r < 4; ++r) {
          const int row = m0 + wm + i * 16 + quad * 4 + r;
          const size_t off = (size_t)row * ldc + col;
          float v = acc[i][j][r];
          if (MODE == 0)      ((bf16*)Cp)[off] = (bf16)v;
          else if (MODE == 1) ((float*)Cp)[off] = v;
          else if (MODE == 2) { v += bv; ((bf16*)Cp)[off] = (bf16)(v * sigmoid_fast(v)); }
          else if (MODE == 3) { v += bv; ((float*)Cp)[off] = (v > 20.f) ? v : log1pf(__expf(v)); }
          else                { v += bv + resid[off]; ((float*)Cp)[off] = v; }
        }
      }
    }
  }
}

// ---------------------------------------------------------------------------
// Depthwise causal conv (k=4) + bias + silu. dir=0: causal; dir=1 anti-causal
// (equivalent to conv on flipped sequence, expressed in original order).
// ---------------------------------------------------------------------------
__global__ __launch_bounds__(256)
void conv_silu_kernel(const bf16* __restrict__ xz, const float* __restrict__ cw,
                      const float* __restrict__ cb, bf16* __restrict__ xc, int dir)
{
  const int idx = blockIdx.x * 256 + threadIdx.x;   // 4096*2048 total
  const int d   = idx & 2047;
  const int pos = idx >> 11;       // 0..4095
  const int l   = pos & 2047;
  const int b   = pos >> 11;
  float w[4];
#pragma unroll
  for (int j = 0; j < 4; ++j) w[j] = cw[d * 4 + j];
  float acc = cb[d];
  if (dir == 0) {
#pragma unroll
    for (int j = 0; j < 4; ++j) {
      const int ll = l - 3 + j;
      if (ll >= 0) acc += w[j] * (float)xz[((size_t)((b << 11) + ll) << 12) + d];
    }
  } else {
#pragma unroll
    for (int j = 0; j < 4; ++j) {
      const int ll = l + 3 - j;
      if (ll < 2048) acc += w[j] * (float)xz[((size_t)((b << 11) + ll) << 12) + d];
    }
  }
  xc[(size_t)pos * 2048 + d] = (bf16)(acc * sigmoid_fast(acc));
}

// ---------------------------------------------------------------------------
// Chunked selective scan — thread per (b, d, chunk); h[16]/A[16] in registers.
// Logical time tau in [0,2048); physical l = dir ? 2047-tau : tau.
//
// S1: local scan from h=0 -> per-chunk decay P[16] and final state F[16].
//     P/F layout: [((b*NCHUNK+c)*2048+d)*16+s] (thread-contiguous 64B).
// S2: per (b,d,s): serial over chunks: Hbuf[c] = H; H = F + P*H.
// S3: recurrence seeded with Hbuf; y = sum_s h[s]*C[s] in registers; fused
//     gate (y + u*D)*silu(z) -> yg (bf16).
// ---------------------------------------------------------------------------
__global__ __launch_bounds__(256)
void scan_part1(const float* __restrict__ dt, const bf16* __restrict__ xc,
                const bf16* __restrict__ xdbl, const float* __restrict__ A_log,
                float* __restrict__ Pbuf, float* __restrict__ Fbuf, int dir)
{
  const int tid = threadIdx.x;
  const int d = blockIdx.x * 256 + tid;   // 0..2047 (grid.x = 8)
  const int c = blockIdx.y;
  const int b = blockIdx.z;

  float Av[16];
#pragma unroll
  for (int q = 0; q < 4; ++q) {
    const float4 a4 = *reinterpret_cast<const float4*>(A_log + d * 16 + q * 4);
    Av[q * 4 + 0] = -__expf(a4.x);
    Av[q * 4 + 1] = -__expf(a4.y);
    Av[q * 4 + 2] = -__expf(a4.z);
    Av[q * 4 + 3] = -__expf(a4.w);
  }

  const int l0  = dir ? (2047 - c * CHUNK) : (c * CHUNK);
  const int stp = dir ? -1 : 1;
  const float* pdt = dt   + (size_t)(b * 2048 + l0) * 2048 + d;
  const bf16*  pxc = xc   + (size_t)(b * 2048 + l0) * 2048 + d;
  const bf16*  pxd = xdbl + (size_t)(b * 2048 + l0) * 96;
  const long sdt = (long)stp * 2048, sxd = (long)stp * 96;

  float h[16], P[16];
#pragma unroll
  for (int s = 0; s < 16; ++s) { h[s] = 0.f; P[s] = 1.f; }

  for (int ti = 0; ti < CHUNK; ++ti) {
    const float dtv = *pdt;
    const float uf  = (float)*pxc;
    const bf16x8 B0 = *reinterpret_cast<const bf16x8*>(pxd + 64);
    const bf16x8 B1 = *reinterpret_cast<const bf16x8*>(pxd + 72);
    const float dtu = dtv * uf;
#pragma unroll
    for (int s = 0; s < 8; ++s) {
      const float e = __expf(dtv * Av[s]);
      h[s] = h[s] * e + dtu * (float)B0[s];
      P[s] *= e;
    }
#pragma unroll
    for (int s = 0; s < 8; ++s) {
      const float e = __expf(dtv * Av[8 + s]);
      h[8 + s] = h[8 + s] * e + dtu * (float)B1[s];
      P[8 + s] *= e;
    }
    pdt += sdt; pxc += sdt; pxd += sxd;
  }

  float* Pp = Pbuf + (((size_t)(b * NCHUNK + c) * 2048) + d) * 16;
  float* Fp = Fbuf + (((size_t)(b * NCHUNK + c) * 2048) + d) * 16;
#pragma unroll
  for (int q = 0; q < 4; ++q) {
    *reinterpret_cast<float4*>(Pp + q * 4) = make_float4(P[q*4], P[q*4+1], P[q*4+2], P[q*4+3]);
    *reinterpret_cast<float4*>(Fp + q * 4) = make_float4(h[q*4], h[q*4+1], h[q*4+2], h[q*4+3]);
  }
}

__global__ __launch_bounds__(256)
void scan_part2(const float* __restrict__ Pbuf, const float* __restrict__ Fbuf,
                float* __restrict__ Hbuf)
{
  const int idx = blockIdx.x * 256 + threadIdx.x;  // 65536 total
  const int s = idx & 15;
  const int d = (idx >> 4) & 2047;
  const int b = idx >> 15;
  float H = 0.0f;
  for (int c = 0; c < NCHUNK; ++c) {
    const size_t off = (((size_t)(b * NCHUNK + c) * 2048) + d) * 16 + s;
    Hbuf[off] = H;
    H = Fbuf[off] + Pbuf[off] * H;
  }
}

__global__ __launch_bounds__(256)
void scan_part3(const float* __restrict__ dt, const bf16* __restrict__ xc,
                const bf16* __restrict__ xdbl, const bf16* __restrict__ xz,
                const float* __restrict__ A_log, const float* __restrict__ Dp,
                const float* __restrict__ Hbuf, bf16* __restrict__ yg, int dir)
{
  const int tid = threadIdx.x;
  const int d = blockIdx.x * 256 + tid;   // 0..2047 (grid.x = 8)
  const int c = blockIdx.y;
  const int b = blockIdx.z;

  float Av[16];
#pragma unroll
  for (int q = 0; q < 4; ++q) {
    const float4 a4 = *reinterpret_cast<const float4*>(A_log + d * 16 + q * 4);
    Av[q * 4 + 0] = -__expf(a4.x);
    Av[q * 4 + 1] = -__expf(a4.y);
    Av[q * 4 + 2] = -__expf(a4.z);
    Av[q * 4 + 3] = -__expf(a4.w);
  }
  const float Dv = Dp[d];

  float h[16];
  const float* Hp = Hbuf + (((size_t)(b * NCHUNK + c) * 2048) + d) * 16;
#pragma unroll
  for (int q = 0; q < 4; ++q) {
    const float4 h4 = *reinterpret_cast<const float4*>(Hp + q * 4);
    h[q * 4 + 0] = h4.x; h[q * 4 + 1] = h4.y; h[q * 4 + 2] = h4.z; h[q * 4 + 3] = h4.w;
  }

  const int l0  = dir ? (2047 - c * CHUNK) : (c * CHUNK);
  const int stp = dir ? -1 : 1;
  const float* pdt = dt   + (size_t)(b * 2048 + l0) * 2048 + d;
  const bf16*  pxc = xc   + (size_t)(b * 2048 + l0) * 2048 + d;
  const bf16*  pxd = xdbl + (size_t)(b * 2048 + l0) * 96;
  const bf16*  pxz = xz   + (size_t)(b * 2048 + l0) * 4096 + 2048 + d;
  bf16*        pyg = yg   + (size_t)(b * 2048 + l0) * 2048 + d;
  const long sdt = (long)stp * 2048, sxd = (long)stp * 96, sxz = (long)stp * 4096;

  for (int ti = 0; ti < CHUNK; ++ti) {
    const float dtv = *pdt;
    const float uf  = (float)*pxc;
    const bf16x8 B0 = *reinterpret_cast<const bf16x8*>(pxd + 64);
    const bf16x8 B1 = *reinterpret_cast<const bf16x8*>(pxd + 72);
    const bf16x8 C0 = *reinterpret_cast<const bf16x8*>(pxd + 80);
    const bf16x8 C1 = *reinterpret_cast<const bf16x8*>(pxd + 88);
    const float dtu = dtv * uf;
    float y = 0.f;
#pragma unroll
    for (int s = 0; s < 8; ++s) {
      const float e = __expf(dtv * Av[s]);
      h[s] = h[s] * e + dtu * (float)B0[s];
      y += h[s] * (float)C0[s];
    }
#pragma unroll
    for (int s = 0; s < 8; ++s) {
      const float e = __expf(dtv * Av[8 + s]);
      h[8 + s] = h[8 + s] * e + dtu * (float)B1[s];
      y += h[8 + s] * (float)C1[s];
    }
    const float zv = (float)*pxz;
    *pyg = (bf16)((y + uf * Dv) * (zv * sigmoid_fast(zv)));
    pdt += sdt; pxc += sdt; pxd += sxd; pxz += sxz; pyg += sdt;
  }
}

// ---------------------------------------------------------------------------
// x1 = x + 0.5*(ym_f + ym_b); store x1 (f32) and LayerNorm(x1)*g+b (bf16).
// ---------------------------------------------------------------------------
__global__ __launch_bounds__(256)
void combine_ln_kernel(const float* __restrict__ x, const float* __restrict__ ymf,
                       const float* __restrict__ ymb, const float* __restrict__ gg,
                       const float* __restrict__ bb, float* __restrict__ x1,
                       bf16* __restrict__ ln)
{
  const int r = blockIdx.x;
  const int tid = threadIdx.x;
  const size_t base = (size_t)r * 1024;
  float v[4];
  float sum = 0.f, sq = 0.f;
#pragma unroll
  for (int i = 0; i < 4; ++i) {
    const int c = tid + i * 256;
    const float t = x[base + c] + 0.5f * (ymf[base + c] + ymb[base + c]);
    v[i] = t; sum += t; sq += t * t;
    x1[base + c] = t;
  }
#pragma unroll
  for (int off = 32; off >= 1; off >>= 1) {
    sum += __shfl_xor(sum, off);
    sq  += __shfl_xor(sq, off);
  }
  __shared__ float s1[4], s2[4];
  const int wave = tid >> 6, lane = tid & 63;
  if (lane == 0) { s1[wave] = sum; s2[wave] = sq; }
  __syncthreads();
  sum = s1[0] + s1[1] + s1[2] + s1[3];
  sq  = s2[0] + s2[1] + s2[2] + s2[3];
  const float mean = sum * (1.0f / 1024.0f);
  const float var  = sq * (1.0f / 1024.0f) - mean * mean;
  const float rs   = rsqrtf(var + 1e-5f);
#pragma unroll
  for (int i = 0; i < 4; ++i) {
    const int c = tid + i * 256;
    ln[base + c] = (bf16)((v[i] - mean) * rs * gg[c] + bb[c]);
  }
}

// ---------------------------------------------------------------------------
extern "C" void kernel_launch(void* const* d_in, const int* in_sizes, int n_in,
                              void* d_out, int out_size, void* d_ws, size_t ws_size,
                              hipStream_t stream)
{
  (void)in_sizes; (void)n_in; (void)out_size; (void)ws_size;

  const float* x      = (const float*)d_in[0];
  const float* ff_ln_g = (const float*)d_in[19];
  const float* ff_ln_b = (const float*)d_in[20];
  const float* ff_w1   = (const float*)d_in[21];
  const float* ff_b1   = (const float*)d_in[22];
  const float* ff_w2   = (const float*)d_in[23];
  const float* ff_b2   = (const float*)d_in[24];

  char* ws = (char*)d_ws;
  size_t off = 0;
  auto alloc = [&](size_t bytes) -> void* {
    void* p = ws + off;
    off += (bytes + 255) & ~(size_t)255;
    return p;
  };
  // M = B*L = 4096 rows everywhere
  bf16*  xz    = (bf16*) alloc((size_t)4096 * 4096 * 2);  // in_proj out (xi | z)
  bf16*  xc    = (bf16*) alloc((size_t)4096 * 2048 * 2);  // conv+silu out
  bf16*  xdbl  = (bf16*) alloc((size_t)4096 * 96 * 2);    // x_proj out
  float* dtb   = (float*)alloc((size_t)4096 * 2048 * 4);  // softplus(dt)
  bf16*  yg    = (bf16*) alloc((size_t)4096 * 2048 * 2);  // gated scan out
  float* ymf   = (float*)alloc((size_t)4096 * 1024 * 4);  // fwd mamba out
  float* ymb   = (float*)alloc((size_t)4096 * 1024 * 4);  // bwd mamba out
  bf16*  xb    = (bf16*) alloc((size_t)4096 * 1024 * 2);  // x as bf16
  bf16*  in_wb = (bf16*) alloc((size_t)4096 * 1024 * 2);  // per-dir in_w bf16
  bf16*  x_wb  = (bf16*) alloc((size_t)96 * 2048 * 2);    // per-dir x_w bf16
  bf16*  dt_wb = (bf16*) alloc((size_t)2048 * 64 * 2);    // per-dir dt_w bf16
  bf16*  out_wb= (bf16*) alloc((size_t)1024 * 2048 * 2);  // per-dir out_w bf16
  float* Pbuf  = (float*)alloc((size_t)2 * NCHUNK * 2048 * 16 * 4);  // 8MB
  float* Fbuf  = (float*)alloc((size_t)2 * NCHUNK * 2048 * 16 * 4);  // 8MB
  float* Hbuf  = (float*)alloc((size_t)2 * NCHUNK * 2048 * 16 * 4);  // 8MB
  // phase-ordered aliases (safe: prior users finish before these are written)
  float* x1     = (float*)dtb;   // residual after mamba combine
  bf16*  ln     = xc;            // layernorm output
  bf16*  h1     = xz;            // ff1 output
  bf16*  ff_w1b = in_wb;         // in_wb dead after bwd in_proj GEMM
  bf16*  ff_w2b = xb;            // xb dead after bwd in_proj GEMM

  // x -> bf16 (once)
  cvt_f32_bf16<<<4096, 256, 0, stream>>>(x, xb, 4096 * 1024);

  for (int dir = 0; dir < 2; ++dir) {
    const float* in_w   = (const float*)d_in[1 + dir * 9 + 0];
    const float* conv_w = (const float*)d_in[1 + dir * 9 + 1];
    const float* conv_b = (const float*)d_in[1 + dir * 9 + 2];
    const float* x_w    = (const float*)d_in[1 + dir * 9 + 3];
    const float* dt_w   = (const float*)d_in[1 + dir * 9 + 4];
    const float* dt_b   = (const float*)d_in[1 + dir * 9 + 5];
    const float* A_log  = (const float*)d_in[1 + dir * 9 + 6];
    const float* Dp     = (const float*)d_in[1 + dir * 9 + 7];
    const float* out_w  = (const float*)d_in[1 + dir * 9 + 8];

    // weight conversions for this direction
    cvt_f32_bf16<<<4096, 256, 0, stream>>>(in_w,  in_wb,  4096 * 1024);
    cvt_f32_bf16<<<192,  256, 0, stream>>>(x_w,   x_wb,   96 * 2048);
    cvt_f32_bf16<<<128,  256, 0, stream>>>(dt_w,  dt_wb,  2048 * 64);
    cvt_f32_bf16<<<2048, 256, 0, stream>>>(out_w, out_wb, 1024 * 2048);

    // xz = x @ in_w^T   (4096 x 4096, K=1024)
    gemm_bt<0><<<dim3(32, 32), 256, 0, stream>>>(xb, 1024, in_wb, 1024, 4096,
                                                 xz, 4096, nullptr, nullptr, 4096, 1024);
    // depthwise conv + silu
    conv_silu_kernel<<<32768, 256, 0, stream>>>(xz, conv_w, conv_b, xc, dir);
    // xdbl = xc @ x_w^T   (4096 x 96, K=2048)
    gemm_bt<0><<<dim3(32, 1), 256, 0, stream>>>(xc, 2048, x_wb, 2048, 96,
                                                xdbl, 96, nullptr, nullptr, 96, 2048);
    // dt = softplus(xdbl[:, :64] @ dt_w^T + dt_b)   (4096 x 2048, K=64)
    gemm_bt<3><<<dim3(32, 16), 256, 0, stream>>>(xdbl, 96, dt_wb, 64, 2048,
                                                 dtb, 2048, dt_b, nullptr, 2048, 64);
    // chunked selective scan + gate fusion
    scan_part1<<<dim3(8, NCHUNK, 2), 256, 0, stream>>>(dtb, xc, xdbl, A_log,
                                                       Pbuf, Fbuf, dir);
    scan_part2<<<256, 256, 0, stream>>>(Pbuf, Fbuf, Hbuf);
    scan_part3<<<dim3(8, NCHUNK, 2), 256, 0, stream>>>(dtb, xc, xdbl, xz, A_log,
                                                       Dp, Hbuf, yg, dir);
    // ym = yg @ out_w^T   (4096 x 1024, K=2048)
    gemm_bt<1><<<dim3(32, 8), 256, 0, stream>>>(yg, 2048, out_wb, 2048, 1024,
                                                dir ? (void*)ymb : (void*)ymf, 1024,
                                                nullptr, nullptr, 1024, 2048);
  }

  // ff weight conversions (into buffers dead after the dir loop)
  cvt_f32_bf16<<<4096, 256, 0, stream>>>(ff_w1, ff_w1b, 4096 * 1024);
  cvt_f32_bf16<<<4096, 256, 0, stream>>>(ff_w2, ff_w2b, 1024 * 4096);

  // x1 = x + 0.5*(ymf+ymb); ln = LN(x1)*g+b
  combine_ln_kernel<<<4096, 256, 0, stream>>>(x, ymf, ymb, ff_ln_g, ff_ln_b, x1, ln);
  // h1 = silu(ln @ ff_w1^T + b1)   (4096 x 4096, K=1024)
  gemm_bt<2><<<dim3(32, 32), 256, 0, stream>>>(ln, 1024, ff_w1b, 1024, 4096,
                                               h1, 4096, ff_b1, nullptr, 4096, 1024);
  // out = x1 + h1 @ ff_w2^T + b2   (4096 x 1024, K=4096) -> d_out (f32)
  gemm_bt<4><<<dim3(32, 8), 256, 0, stream>>>(h1, 4096, ff_w2b, 4096, 1024,
                                              d_out, 1024, ff_b2, x1, 1024, 4096);
}

// Round 6
// 781.815 us; speedup vs baseline: 5.0193x; 1.2479x over previous
//
#include <hip/hip_runtime.h>

typedef __bf16 bf16;
typedef __bf16 bf16x8 __attribute__((ext_vector_type(8)));
typedef float floatx4 __attribute__((ext_vector_type(4)));

#define LDS_ASYNC(gptr, lptr) \
  __builtin_amdgcn_global_load_lds((const __attribute__((address_space(1))) void*)(gptr), \
                                   (__attribute__((address_space(3))) void*)(lptr), 16, 0, 0)

__device__ __forceinline__ float sigmoid_fast(float x) {
  return 1.0f / (1.0f + __expf(-x));
}

// Chunked scan parameters: L=2048 = NCHUNK * CHUNK
#define CHUNK  64
#define NCHUNK 32

// ---------------------------------------------------------------------------
__global__ __launch_bounds__(256)
void cvt_f32_bf16(const float* __restrict__ src, bf16* __restrict__ dst, int n)
{
  const int i = (blockIdx.x * 256 + threadIdx.x) * 4;
  if (i < n) {
    const float4 v = *reinterpret_cast<const float4*>(src + i);
    dst[i]     = (bf16)v.x;
    dst[i + 1] = (bf16)v.y;
    dst[i + 2] = (bf16)v.z;
    dst[i + 3] = (bf16)v.w;
  }
}

// pack two 2048-float vectors into one 4096-float buffer (replaces memcpys)
__global__ __launch_bounds__(256)
void pack2_kernel(const float* __restrict__ a, const float* __restrict__ b,
                  float* __restrict__ dst)
{
  const int i = blockIdx.x * 256 + threadIdx.x;   // 4096
  dst[i] = (i < 2048) ? a[i] : b[i - 2048];
}

// ---------------------------------------------------------------------------
// Generic MFMA GEMM:  C[m,n] = sum_k A[m,k] * W[n,k]
//   128x128 tile, BK=32, 16x16x32 bf16 MFMA, global_load_lds width-16 staging.
//   z-batching via *StrideZ; K-split via blockIdx.y = ntile + nTilesY*kchunk.
// MODE 0: bf16   MODE 1: f32   MODE 2: bf16 silu(acc+bias)   MODE 3: bf16 softplus(acc+bias)
// ---------------------------------------------------------------------------
template<int MODE, int KSPLIT>
__global__ __launch_bounds__(256)
void gemm_bt(const bf16* __restrict__ A, int lda,
             const bf16* __restrict__ W, int ldw, int wrows,
             void* __restrict__ Cp, int ldc,
             const float* __restrict__ bias,
             int Nstore, int K, int nTilesY,
             size_t aStrideZ, size_t wStrideZ, size_t cStrideZ,
             size_t biasStrideZ, size_t kPartStride)
{
  __shared__ __align__(16) bf16 As[128 * 32];
  __shared__ __align__(16) bf16 Bs[128 * 32];

  const int tid = threadIdx.x;
  const int bz = blockIdx.z;
  int ntile, kc;
  if (KSPLIT > 1) { ntile = blockIdx.y % nTilesY; kc = blockIdx.y / nTilesY; }
  else            { ntile = blockIdx.y; kc = 0; }

  A += (size_t)bz * aStrideZ;
  W += (size_t)bz * wStrideZ;
  if (MODE == 2 || MODE == 3) bias += (size_t)bz * biasStrideZ;
  const size_t coff = (size_t)bz * cStrideZ + (size_t)kc * kPartStride;

  const int m0 = blockIdx.x * 128;
  const int n0 = ntile * 128;
  const int Kc = K / KSPLIT;
  const int kbeg = kc * Kc, kend = kbeg + Kc;

  const int srow  = tid >> 2;         // 0..63
  const int skcol = (tid & 3) * 8;    // 0,8,16,24

  int wr0 = n0 + srow;      if (wr0 > wrows - 1) wr0 = wrows - 1;
  int wr1 = n0 + 64 + srow; if (wr1 > wrows - 1) wr1 = wrows - 1;

  floatx4 acc[4][4];
#pragma unroll
  for (int i = 0; i < 4; ++i)
#pragma unroll
    for (int j = 0; j < 4; ++j)
      acc[i][j] = (floatx4){0.f, 0.f, 0.f, 0.f};

  const int wave = tid >> 6;
  const int lane = tid & 63;
  const int quad = lane >> 4;
  const int l16  = lane & 15;
  const int wm = (wave & 1) * 64;
  const int wn = (wave >> 1) * 64;

  for (int k0 = kbeg; k0 < kend; k0 += 32) {
    __syncthreads();
    LDS_ASYNC(A + (size_t)(m0 + srow) * lda + k0 + skcol,      &As[srow * 32 + skcol]);
    LDS_ASYNC(A + (size_t)(m0 + 64 + srow) * lda + k0 + skcol, &As[(64 + srow) * 32 + skcol]);
    LDS_ASYNC(W + (size_t)wr0 * ldw + k0 + skcol,              &Bs[srow * 32 + skcol]);
    LDS_ASYNC(W + (size_t)wr1 * ldw + k0 + skcol,              &Bs[(64 + srow) * 32 + skcol]);
    __builtin_amdgcn_s_waitcnt(0);
    __syncthreads();

    bf16x8 af[4], bfr[4];
#pragma unroll
    for (int i = 0; i < 4; ++i)
      af[i] = *reinterpret_cast<const bf16x8*>(&As[(wm + i * 16 + l16) * 32 + quad * 8]);
#pragma unroll
    for (int j = 0; j < 4; ++j)
      bfr[j] = *reinterpret_cast<const bf16x8*>(&Bs[(wn + j * 16 + l16) * 32 + quad * 8]);
#pragma unroll
    for (int i = 0; i < 4; ++i)
#pragma unroll
      for (int j = 0; j < 4; ++j)
        acc[i][j] = __builtin_amdgcn_mfma_f32_16x16x32_bf16(af[i], bfr[j], acc[i][j], 0, 0, 0);
  }

  // epilogue — C/D layout: col = lane&15, row = quad*4 + reg  [m89-verified]
#pragma unroll
  for (int j = 0; j < 4; ++j) {
    const int col = n0 + wn + j * 16 + l16;
    if (col < Nstore) {
      float bv = 0.0f;
      if (MODE == 2 || MODE == 3) bv = bias[col];
#pragma unroll
      for (int i = 0; i < 4; ++i) {
#pragma unroll
        for (int r = 0; r < 4; ++r) {
          const int row = m0 + wm + i * 16 + quad * 4 + r;
          const size_t off = coff + (size_t)row * ldc + col;
          float v = acc[i][j][r];
          if (MODE == 0)      ((bf16*)Cp)[off] = (bf16)v;
          else if (MODE == 1) ((float*)Cp)[off] = v;
          else if (MODE == 2) { v += bv; ((bf16*)Cp)[off] = (bf16)(v * sigmoid_fast(v)); }
          else                { v += bv; ((bf16*)Cp)[off] = (bf16)((v > 20.f) ? v : log1pf(__expf(v))); }
        }
      }
    }
  }
}

// ---------------------------------------------------------------------------
// Depthwise conv (k=4) + bias + silu, both directions in one launch.
// xi_all: [dir][4096 rows][2048 cols] bf16. dir=0 causal, dir=1 anti-causal.
// ---------------------------------------------------------------------------
__global__ __launch_bounds__(256)
void conv_silu_kernel(const bf16* __restrict__ xi_all,
                      const float* __restrict__ cw_f, const float* __restrict__ cb_f,
                      const float* __restrict__ cw_b, const float* __restrict__ cb_b,
                      bf16* __restrict__ xc2)
{
  const int idx = blockIdx.x * 256 + threadIdx.x;   // 2*4096*2048 total
  const int d   = idx & 2047;
  const int pos = (idx >> 11) & 4095;
  const int dir = idx >> 23;
  const int l   = pos & 2047;
  const int b   = pos >> 11;
  const float* cw = dir ? cw_b : cw_f;
  const float* cb = dir ? cb_b : cb_f;
  const size_t dbase = (size_t)dir * 4096 * 2048;
  float w[4];
#pragma unroll
  for (int j = 0; j < 4; ++j) w[j] = cw[d * 4 + j];
  float acc = cb[d];
  if (dir == 0) {
#pragma unroll
    for (int j = 0; j < 4; ++j) {
      const int ll = l - 3 + j;
      if (ll >= 0) acc += w[j] * (float)xi_all[dbase + (size_t)((b << 11) + ll) * 2048 + d];
    }
  } else {
#pragma unroll
    for (int j = 0; j < 4; ++j) {
      const int ll = l + 3 - j;
      if (ll < 2048) acc += w[j] * (float)xi_all[dbase + (size_t)((b << 11) + ll) * 2048 + d];
    }
  }
  xc2[dbase + (size_t)pos * 2048 + d] = (bf16)(acc * sigmoid_fast(acc));
}

// ---------------------------------------------------------------------------
// x_proj split-K reduce: xdbl2[dir][r] = sum_ks xpart[dir][ks][r] (bf16)
// ---------------------------------------------------------------------------
__global__ __launch_bounds__(256)
void xproj_reduce(const float* __restrict__ part, bf16* __restrict__ xdbl2)
{
  const int i = blockIdx.x * 256 + threadIdx.x;    // 2*4096*96
  const int dir = i / 393216;
  const int r   = i - dir * 393216;
  const size_t base = (size_t)dir * 4 * 393216 + r;
  const float s = part[base] + part[base + 393216] + part[base + 2 * 393216]
                + part[base + 3 * 393216];
  xdbl2[i] = (bf16)s;
}

// ---------------------------------------------------------------------------
// Chunked selective scan, batched over (dir, b) via blockIdx.z = dir*2+b.
// Thread per (d, chunk); h[16]/A[16] in registers.
// ---------------------------------------------------------------------------
__global__ __launch_bounds__(256)
void scan_part1(const bf16* __restrict__ dt, const bf16* __restrict__ xc,
                const bf16* __restrict__ xdbl,
                const float* __restrict__ Af, const float* __restrict__ Ab,
                float* __restrict__ Pbuf, float* __restrict__ Fbuf)
{
  const int tid = threadIdx.x;
  const int d = blockIdx.x * 256 + tid;   // 0..2047 (grid.x = 8)
  const int c = blockIdx.y;
  const int z = blockIdx.z;
  const int dir = z >> 1, b = z & 1;
  const float* A_log = dir ? Ab : Af;

  float Av[16];
#pragma unroll
  for (int q = 0; q < 4; ++q) {
    const float4 a4 = *reinterpret_cast<const float4*>(A_log + d * 16 + q * 4);
    Av[q * 4 + 0] = -__expf(a4.x);
    Av[q * 4 + 1] = -__expf(a4.y);
    Av[q * 4 + 2] = -__expf(a4.z);
    Av[q * 4 + 3] = -__expf(a4.w);
  }

  const int l0  = dir ? (2047 - c * CHUNK) : (c * CHUNK);
  const int stp = dir ? -1 : 1;
  const size_t dirOff = (size_t)dir * 4096 * 2048;
  const bf16* pdt = dt + dirOff + (size_t)(b * 2048 + l0) * 2048 + d;
  const bf16* pxc = xc + dirOff + (size_t)(b * 2048 + l0) * 2048 + d;
  const bf16* pxd = xdbl + (size_t)dir * 4096 * 96 + (size_t)(b * 2048 + l0) * 96;
  const long sdt = (long)stp * 2048, sxd = (long)stp * 96;

  float h[16], P[16];
#pragma unroll
  for (int s = 0; s < 16; ++s) { h[s] = 0.f; P[s] = 1.f; }

  for (int ti = 0; ti < CHUNK; ++ti) {
    const float dtv = (float)*pdt;
    const float uf  = (float)*pxc;
    const bf16x8 B0 = *reinterpret_cast<const bf16x8*>(pxd + 64);
    const bf16x8 B1 = *reinterpret_cast<const bf16x8*>(pxd + 72);
    const float dtu = dtv * uf;
#pragma unroll
    for (int s = 0; s < 8; ++s) {
      const float e = __expf(dtv * Av[s]);
      h[s] = h[s] * e + dtu * (float)B0[s];
      P[s] *= e;
    }
#pragma unroll
    for (int s = 0; s < 8; ++s) {
      const float e = __expf(dtv * Av[8 + s]);
      h[8 + s] = h[8 + s] * e + dtu * (float)B1[s];
      P[8 + s] *= e;
    }
    pdt += sdt; pxc += sdt; pxd += sxd;
  }

  float* Pp = Pbuf + (((size_t)(z * NCHUNK + c) * 2048) + d) * 16;
  float* Fp = Fbuf + (((size_t)(z * NCHUNK + c) * 2048) + d) * 16;
#pragma unroll
  for (int q = 0; q < 4; ++q) {
    *reinterpret_cast<float4*>(Pp + q * 4) = make_float4(P[q*4], P[q*4+1], P[q*4+2], P[q*4+3]);
    *reinterpret_cast<float4*>(Fp + q * 4) = make_float4(h[q*4], h[q*4+1], h[q*4+2], h[q*4+3]);
  }
}

// In-place: FH holds F on entry, H (entering state per chunk) on exit.
__global__ __launch_bounds__(256)
void scan_part2(const float* __restrict__ Pbuf, float* __restrict__ FH)
{
  const int idx = blockIdx.x * 256 + threadIdx.x;  // 4*2048*16 = 131072
  const int s = idx & 15;
  const int d = (idx >> 4) & 2047;
  const int z = idx >> 15;
  float H = 0.0f;
  for (int c = 0; c < NCHUNK; ++c) {
    const size_t off = (((size_t)(z * NCHUNK + c) * 2048) + d) * 16 + s;
    const float f = FH[off];
    const float p = Pbuf[off];
    FH[off] = H;
    H = f + p * H;
  }
}

__global__ __launch_bounds__(256)
void scan_part3(const bf16* __restrict__ dt, const bf16* __restrict__ xc,
                const bf16* __restrict__ xdbl, const bf16* __restrict__ z_all,
                const float* __restrict__ Af, const float* __restrict__ Ab,
                const float* __restrict__ Df, const float* __restrict__ Db,
                const float* __restrict__ Hbuf, bf16* __restrict__ yg2)
{
  const int tid = threadIdx.x;
  const int d = blockIdx.x * 256 + tid;
  const int c = blockIdx.y;
  const int z = blockIdx.z;
  const int dir = z >> 1, b = z & 1;
  const float* A_log = dir ? Ab : Af;

  float Av[16];
#pragma unroll
  for (int q = 0; q < 4; ++q) {
    const float4 a4 = *reinterpret_cast<const float4*>(A_log + d * 16 + q * 4);
    Av[q * 4 + 0] = -__expf(a4.x);
    Av[q * 4 + 1] = -__expf(a4.y);
    Av[q * 4 + 2] = -__expf(a4.z);
    Av[q * 4 + 3] = -__expf(a4.w);
  }
  const float Dv = dir ? Db[d] : Df[d];

  float h[16];
  const float* Hp = Hbuf + (((size_t)(z * NCHUNK + c) * 2048) + d) * 16;
#pragma unroll
  for (int q = 0; q < 4; ++q) {
    const float4 h4 = *reinterpret_cast<const float4*>(Hp + q * 4);
    h[q * 4 + 0] = h4.x; h[q * 4 + 1] = h4.y; h[q * 4 + 2] = h4.z; h[q * 4 + 3] = h4.w;
  }

  const int l0  = dir ? (2047 - c * CHUNK) : (c * CHUNK);
  const int stp = dir ? -1 : 1;
  const size_t dirOff = (size_t)dir * 4096 * 2048;
  const bf16* pdt = dt + dirOff + (size_t)(b * 2048 + l0) * 2048 + d;
  const bf16* pxc = xc + dirOff + (size_t)(b * 2048 + l0) * 2048 + d;
  const bf16* pxd = xdbl + (size_t)dir * 4096 * 96 + (size_t)(b * 2048 + l0) * 96;
  const bf16* pxz = z_all + dirOff + (size_t)(b * 2048 + l0) * 2048 + d;
  bf16*       pyg = yg2 + dirOff + (size_t)(b * 2048 + l0) * 2048 + d;
  const long sdt = (long)stp * 2048, sxd = (long)stp * 96;

  for (int ti = 0; ti < CHUNK; ++ti) {
    const float dtv = (float)*pdt;
    const float uf  = (float)*pxc;
    const bf16x8 B0 = *reinterpret_cast<const bf16x8*>(pxd + 64);
    const bf16x8 B1 = *reinterpret_cast<const bf16x8*>(pxd + 72);
    const bf16x8 C0 = *reinterpret_cast<const bf16x8*>(pxd + 80);
    const bf16x8 C1 = *reinterpret_cast<const bf16x8*>(pxd + 88);
    const float dtu = dtv * uf;
    float y = 0.f;
#pragma unroll
    for (int s = 0; s < 8; ++s) {
      const float e = __expf(dtv * Av[s]);
      h[s] = h[s] * e + dtu * (float)B0[s];
      y += h[s] * (float)C0[s];
    }
#pragma unroll
    for (int s = 0; s < 8; ++s) {
      const float e = __expf(dtv * Av[8 + s]);
      h[8 + s] = h[8 + s] * e + dtu * (float)B1[s];
      y += h[8 + s] * (float)C1[s];
    }
    const float zv = (float)*pxz;
    *pyg = (bf16)((y + uf * Dv) * (zv * sigmoid_fast(zv)));
    pdt += sdt; pxc += sdt; pxd += sxd; pxz += sdt; pyg += sdt;
  }
}

// ---------------------------------------------------------------------------
// x1 = x + 0.5*(ym_f + ym_b); store x1 (f32) and LayerNorm(x1)*g+b (bf16).
// ---------------------------------------------------------------------------
__global__ __launch_bounds__(256)
void combine_ln_kernel(const float* __restrict__ x, const bf16* __restrict__ ym,
                       const float* __restrict__ gg, const float* __restrict__ bb,
                       float* __restrict__ x1, bf16* __restrict__ ln)
{
  const int r = blockIdx.x;
  const int tid = threadIdx.x;
  const size_t base = (size_t)r * 1024;
  const bf16* ymf = ym;
  const bf16* ymb = ym + (size_t)4096 * 1024;
  float v[4];
  float sum = 0.f, sq = 0.f;
#pragma unroll
  for (int i = 0; i < 4; ++i) {
    const int c = tid + i * 256;
    const float t = x[base + c] + 0.5f * ((float)ymf[base + c] + (float)ymb[base + c]);
    v[i] = t; sum += t; sq += t * t;
    x1[base + c] = t;
  }
#pragma unroll
  for (int off = 32; off >= 1; off >>= 1) {
    sum += __shfl_xor(sum, off);
    sq  += __shfl_xor(sq, off);
  }
  __shared__ float s1[4], s2[4];
  const int wave = tid >> 6, lane = tid & 63;
  if (lane == 0) { s1[wave] = sum; s2[wave] = sq; }
  __syncthreads();
  sum = s1[0] + s1[1] + s1[2] + s1[3];
  sq  = s2[0] + s2[1] + s2[2] + s2[3];
  const float mean = sum * (1.0f / 1024.0f);
  const float var  = sq * (1.0f / 1024.0f) - mean * mean;
  const float rs   = rsqrtf(var + 1e-5f);
#pragma unroll
  for (int i = 0; i < 4; ++i) {
    const int c = tid + i * 256;
    ln[base + c] = (bf16)((v[i] - mean) * rs * gg[c] + bb[c]);
  }
}

// ---------------------------------------------------------------------------
// ff2 split-K2 reduce: out = part0 + part1 + b2[col] + x1  (f32 -> d_out)
// ---------------------------------------------------------------------------
__global__ __launch_bounds__(256)
void ff2_reduce(const float* __restrict__ part, const float* __restrict__ x1,
                const float* __restrict__ b2, float* __restrict__ out)
{
  const int i = (blockIdx.x * 256 + threadIdx.x) * 4;   // over 4096*1024
  const int col = i & 1023;
  const size_t P = (size_t)4096 * 1024;
  float4 s0 = *reinterpret_cast<const float4*>(part + i);
  const float4 s1 = *reinterpret_cast<const float4*>(part + P + i);
  const float4 xv = *reinterpret_cast<const float4*>(x1 + i);
  const float4 bv = *reinterpret_cast<const float4*>(b2 + col);
  s0.x += s1.x + xv.x + bv.x;
  s0.y += s1.y + xv.y + bv.y;
  s0.z += s1.z + xv.z + bv.z;
  s0.w += s1.w + xv.w + bv.w;
  *reinterpret_cast<float4*>(out + i) = s0;
}

// ---------------------------------------------------------------------------
extern "C" void kernel_launch(void* const* d_in, const int* in_sizes, int n_in,
                              void* d_out, int out_size, void* d_ws, size_t ws_size,
                              hipStream_t stream)
{
  (void)in_sizes; (void)n_in; (void)out_size; (void)ws_size;

  const float* x       = (const float*)d_in[0];
  const float* ff_ln_g = (const float*)d_in[19];
  const float* ff_ln_b = (const float*)d_in[20];
  const float* ff_w1   = (const float*)d_in[21];
  const float* ff_b1   = (const float*)d_in[22];
  const float* ff_w2   = (const float*)d_in[23];
  const float* ff_b2   = (const float*)d_in[24];
  const float* in_w[2]   = {(const float*)d_in[1],  (const float*)d_in[10]};
  const float* conv_w[2] = {(const float*)d_in[2],  (const float*)d_in[11]};
  const float* conv_b[2] = {(const float*)d_in[3],  (const float*)d_in[12]};
  const float* x_w[2]    = {(const float*)d_in[4],  (const float*)d_in[13]};
  const float* dt_w[2]   = {(const float*)d_in[5],  (const float*)d_in[14]};
  const float* dt_b[2]   = {(const float*)d_in[6],  (const float*)d_in[15]};
  const float* A_log[2]  = {(const float*)d_in[7],  (const float*)d_in[16]};
  const float* Dp[2]     = {(const float*)d_in[8],  (const float*)d_in[17]};
  const float* out_w[2]  = {(const float*)d_in[9],  (const float*)d_in[18]};

  // ---------------------------------------------------------------------
  // Explicit phase-aliased workspace layout (total 178 MiB + 16 KiB).
  // Phases: P0 cvt, P1 in_proj(xi,z), P2 conv, P3 x_proj(+reduce), P4 dt,
  //         P5 scan1, P6 scan2, P7 scan3, P8 out_proj, P9 combine_ln,
  //         P10 cvt ffw, P11 ff1, P12 ff2, P13 ff2_reduce
  // ---------------------------------------------------------------------
  char* ws = (char*)d_ws;
  const size_t Mi = 1 << 20;
  // R0 [0,32Mi): xi_all (P1-P2) -> dtb2 (P4-P7) -> x1 f32 16Mi (P9-P13)
  bf16*  xi_all = (bf16*)(ws + 0);
  bf16*  dtb2   = (bf16*)(ws + 0);
  float* x1     = (float*)(ws + 0);
  // R1 [32Mi,64Mi): z_all (P1-P7) -> h1 (P11-P12)
  bf16*  z_all  = (bf16*)(ws + 32 * Mi);
  bf16*  h1     = (bf16*)(ws + 32 * Mi);
  // R2 [64Mi,96Mi): xc2 (P2-P7) -> ln 8Mi (P9-P11)
  bf16*  xc2    = (bf16*)(ws + 64 * Mi);
  bf16*  ln     = (bf16*)(ws + 64 * Mi);
  // R3 [96Mi,128Mi): inwball 16Mi (P0-P1) -> yg2 (P7-P8) -> ffw1b 8Mi (P10-P11)
  //                  -> ff2part f32 32Mi (P12-P13)
  bf16*  inwball= (bf16*)(ws + 96 * Mi);
  bf16*  yg2    = (bf16*)(ws + 96 * Mi);
  bf16*  ffw1b  = (bf16*)(ws + 96 * Mi);
  float* ff2part= (float*)(ws + 96 * Mi);
  // R4 [128Mi,144Mi): xpart 12Mi (P3) -> Pbuf 16Mi (P5-P6) -> ym 16Mi (P8-P9)
  float* xpart  = (float*)(ws + 128 * Mi);
  float* Pbuf   = (float*)(ws + 128 * Mi);
  bf16*  ym     = (bf16*)(ws + 128 * Mi);
  // R5 [144Mi,160Mi): Fbuf/Hbuf 16Mi (P5-P7) -> ffw2b 8Mi (P10-P12)
  float* Fbuf   = (float*)(ws + 144 * Mi);
  bf16*  ffw2b  = (bf16*)(ws + 144 * Mi);
  // R6 [160Mi,168Mi): xb 8Mi (P0-P1) -> xdbl2 1.5Mi (P3-P7)
  bf16*  xb     = (bf16*)(ws + 160 * Mi);
  bf16*  xdbl2  = (bf16*)(ws + 160 * Mi);
  // R7 [168Mi,176Mi): outwb2 8Mi (P0-P8)
  bf16*  outwb2 = (bf16*)(ws + 168 * Mi);
  // R8 [176Mi,...): xwb2 0.75Mi, dtwb2 0.5Mi, dtbias2 16KiB
  bf16*  xwb2   = (bf16*)(ws + 176 * Mi);
  bf16*  dtwb2  = (bf16*)(ws + 177 * Mi);
  float* dtbias2= (float*)(ws + 1862 * (Mi / 10) + 0);  // placed below
  dtbias2 = (float*)(ws + 177 * Mi + 512 * 1024);       // after dtwb2 (0.5Mi)

  // ---- P0: weight conversions ----
  cvt_f32_bf16<<<4096, 256, 0, stream>>>(x, xb, 4096 * 1024);
  cvt_f32_bf16<<<4096, 256, 0, stream>>>(in_w[0], inwball, 4096 * 1024);
  cvt_f32_bf16<<<4096, 256, 0, stream>>>(in_w[1], inwball + (size_t)4096 * 1024, 4096 * 1024);
  cvt_f32_bf16<<<192,  256, 0, stream>>>(x_w[0],  xwb2, 96 * 2048);
  cvt_f32_bf16<<<192,  256, 0, stream>>>(x_w[1],  xwb2 + 96 * 2048, 96 * 2048);
  cvt_f32_bf16<<<128,  256, 0, stream>>>(dt_w[0], dtwb2, 2048 * 64);
  cvt_f32_bf16<<<128,  256, 0, stream>>>(dt_w[1], dtwb2 + 2048 * 64, 2048 * 64);
  cvt_f32_bf16<<<2048, 256, 0, stream>>>(out_w[0], outwb2, 1024 * 2048);
  cvt_f32_bf16<<<2048, 256, 0, stream>>>(out_w[1], outwb2 + (size_t)1024 * 2048, 1024 * 2048);
  pack2_kernel<<<16, 256, 0, stream>>>(dt_b[0], dt_b[1], dtbias2);

  // ---- P1: in_proj, two z-batched dispatches (xi rows [0,2048), z rows [2048,4096))
  gemm_bt<0, 1><<<dim3(32, 16, 2), 256, 0, stream>>>(
      xb, 1024, inwball, 1024, 2048, xi_all, 2048, nullptr,
      2048, 1024, 16, 0, (size_t)4096 * 1024, (size_t)4096 * 2048, 0, 0);
  gemm_bt<0, 1><<<dim3(32, 16, 2), 256, 0, stream>>>(
      xb, 1024, inwball + (size_t)2048 * 1024, 1024, 2048, z_all, 2048, nullptr,
      2048, 1024, 16, 0, (size_t)4096 * 1024, (size_t)4096 * 2048, 0, 0);

  // ---- P2: depthwise conv + silu, both dirs
  conv_silu_kernel<<<65536, 256, 0, stream>>>(xi_all, conv_w[0], conv_b[0],
                                              conv_w[1], conv_b[1], xc2);

  // ---- P3: x_proj, dir-batched + split-K4, then reduce
  gemm_bt<1, 4><<<dim3(32, 4, 2), 256, 0, stream>>>(
      xc2, 2048, xwb2, 2048, 96, xpart, 96, nullptr,
      96, 2048, 1,
      (size_t)4096 * 2048, (size_t)96 * 2048, (size_t)4 * 4096 * 96, 0,
      (size_t)4096 * 96);
  xproj_reduce<<<3072, 256, 0, stream>>>(xpart, xdbl2);

  // ---- P4: dt = softplus(xdbl[:, :64] @ dt_w^T + dt_b), dir-batched (K=64)
  gemm_bt<3, 1><<<dim3(32, 16, 2), 256, 0, stream>>>(
      xdbl2, 96, dtwb2, 64, 2048, dtb2, 2048, dtbias2,
      2048, 64, 16,
      (size_t)4096 * 96, (size_t)2048 * 64, (size_t)4096 * 2048, 2048, 0);

  // ---- P5-P7: chunked selective scan (batched over dir x batch)
  scan_part1<<<dim3(8, NCHUNK, 4), 256, 0, stream>>>(dtb2, xc2, xdbl2,
                                                     A_log[0], A_log[1], Pbuf, Fbuf);
  scan_part2<<<512, 256, 0, stream>>>(Pbuf, Fbuf);  // Fbuf becomes Hbuf in-place
  scan_part3<<<dim3(8, NCHUNK, 4), 256, 0, stream>>>(dtb2, xc2, xdbl2, z_all,
                                                     A_log[0], A_log[1], Dp[0], Dp[1],
                                                     Fbuf, yg2);

  // ---- P8: out_proj, dir-batched: ym[dir] = yg2[dir] @ outw[dir]^T (bf16)
  gemm_bt<0, 1><<<dim3(32, 8, 2), 256, 0, stream>>>(
      yg2, 2048, outwb2, 2048, 1024, ym, 1024, nullptr,
      1024, 2048, 8,
      (size_t)4096 * 2048, (size_t)1024 * 2048, (size_t)4096 * 1024, 0, 0);

  // ---- P9: x1 = x + 0.5*(ymf+ymb); ln = LN(x1)*g+b
  combine_ln_kernel<<<4096, 256, 0, stream>>>(x, ym, ff_ln_g, ff_ln_b, x1, ln);

  // ---- P10: ff weights (into regions dead after scan/out_proj)
  cvt_f32_bf16<<<4096, 256, 0, stream>>>(ff_w1, ffw1b, 4096 * 1024);
  cvt_f32_bf16<<<4096, 256, 0, stream>>>(ff_w2, ffw2b, 1024 * 4096);

  // ---- P11: h1 = silu(ln @ ff_w1^T + b1)   (4096 x 4096, K=1024)
  gemm_bt<2, 1><<<dim3(32, 32, 1), 256, 0, stream>>>(
      ln, 1024, ffw1b, 1024, 4096, h1, 4096, ff_b1,
      4096, 1024, 32, 0, 0, 0, 0, 0);

  // ---- P12-P13: ff2 split-K2 + reduce (bias + residual) -> d_out (f32)
  gemm_bt<1, 2><<<dim3(32, 16, 1), 256, 0, stream>>>(
      h1, 4096, ffw2b, 4096, 1024, ff2part, 1024, nullptr,
      1024, 4096, 8, 0, 0, 0, 0, (size_t)4096 * 1024);
  ff2_reduce<<<4096, 256, 0, stream>>>(ff2part, x1, ff_b2, (float*)d_out);
}